// Round 7
// baseline (336.555 us; speedup 1.0000x reference)
//
#include <hip/hip_runtime.h>
#include <hip/hip_bf16.h>

// Problem constants (GATLayer): B=8, C=2048, IN=OUT=128, H=4, D=32
constexpr int B_  = 8;
constexpr int C_  = 2048;
constexpr int IND = 128;
constexpr int H_  = 4;
constexpr int D_  = 32;
constexpr int M_  = B_ * C_;          // 16384 tokens
constexpr float QSCALE = 0.17677669529663687f;   // 1/sqrt(32)
constexpr float L2E    = 1.4426950408889634f;
constexpr float QL2    = QSCALE * L2E;           // folded into Wt Q-rows

constexpr int KSPLIT = 4;             // global split (Opart = 33.6 MB, ws fits)
constexpr int KPG = C_ / KSPLIT;      // 512 keys per (block, kz)

typedef __attribute__((ext_vector_type(8))) short short8;
typedef __attribute__((ext_vector_type(4))) short s4t;
typedef __attribute__((ext_vector_type(4))) float f4t;
typedef __attribute__((ext_vector_type(4))) unsigned short us4;

// Device pass has these; host pass doesn't advertise via __has_builtin.
#if __has_builtin(__builtin_amdgcn_mfma_f32_16x16x16bf16_1k)
#define MFMA16(a, b, c) __builtin_amdgcn_mfma_f32_16x16x16bf16_1k(a, b, c, 0, 0, 0)
#else
#define MFMA16(a, b, c) (c)   // host-pass placeholder
#endif
#define MFMA32(a, b, c) __builtin_amdgcn_mfma_f32_16x16x32_bf16(a, b, c, 0, 0, 0)

__device__ __forceinline__ unsigned short f2bf(float f) {
    union { float f; unsigned u; } v; v.f = f;
    unsigned u = v.u + 0x7fffu + ((v.u >> 16) & 1u);   // RNE
    return (unsigned short)(u >> 16);
}

__device__ __forceinline__ s4t pack4_bf16(float p0, float p1, float p2, float p3) {
#if __has_builtin(__builtin_amdgcn_cvt_pk_bf16_f32)
    auto a = __builtin_amdgcn_cvt_pk_bf16_f32(p0, p1);
    auto b = __builtin_amdgcn_cvt_pk_bf16_f32(p2, p3);
    unsigned u[2];
    __builtin_memcpy(&u[0], &a, 4);
    __builtin_memcpy(&u[1], &b, 4);
    s4t pp;
    __builtin_memcpy(&pp, u, 8);
    return pp;
#else
    s4t pp;
    pp[0] = (short)f2bf(p0); pp[1] = (short)f2bf(p1);
    pp[2] = (short)f2bf(p2); pp[3] = (short)f2bf(p3);
    return pp;
#endif
}

__device__ __forceinline__ short8 cvt8(float4 a, float4 b) {
    s4t x = pack4_bf16(a.x, a.y, a.z, a.w);
    s4t y = pack4_bf16(b.x, b.y, b.z, b.w);
    short8 r;
    r[0] = x[0]; r[1] = x[1]; r[2] = x[2]; r[3] = x[3];
    r[4] = y[0]; r[5] = y[1]; r[6] = y[2]; r[7] = y[3];
    return r;
}

// ---------------------------------------------------------------------------
// K0: weight prep. Wtb[512][128] bf16: row n = column n of the fused weight
// [Wq*QL2 | Wk | Wv | Wo].  LDS tile transpose, padded stride.
__global__ __launch_bounds__(256) void prep_w_kernel(
    const float* __restrict__ Wq, const float* __restrict__ Wk,
    const float* __restrict__ Wv, const float* __restrict__ Wo,
    unsigned short* __restrict__ Wtb)
{
    __shared__ unsigned short lds[16][130];
    const int t  = threadIdx.x;
    const int n0 = blockIdx.x * 16;          // 0..511 in steps of 16

    const float* src; int nb; float sc = 1.0f;
    if      (n0 < 128) { src = Wq; nb = n0;       sc = QL2; }
    else if (n0 < 256) { src = Wk; nb = n0 - 128; }
    else if (n0 < 384) { src = Wv; nb = n0 - 256; }
    else               { src = Wo; nb = n0 - 384; }

    const int nn = t & 15, kk = t >> 4;      // kk: 0..15
#pragma unroll
    for (int kb = 0; kb < 8; ++kb) {
        const int k = kb * 16 + kk;
        lds[nn][k] = f2bf(src[k * IND + nb + nn] * sc);
    }
    __syncthreads();
    const int k = t & 127, rr = t >> 7;      // rr: 0..1
#pragma unroll
    for (int it = 0; it < 8; ++it) {
        const int r = it * 2 + rr;
        Wtb[(size_t)(n0 + r) * IND + k] = lds[r][k];
    }
}

// ---------------------------------------------------------------------------
// K1: QKV projection via MFMA. Block = 192 = 3 waves (one per matrix);
// grid (M/16, 2): grid.y splits the 8 N-tiles into two halves -> 6144 waves.
// Q/K computed TRANSPOSED (coalesced 8B row stores); V computed normal ->
// lands directly in Vt[b][d][c] layout.
__global__ __launch_bounds__(192) void qkv_proj_kernel(
    const float* __restrict__ x, const unsigned short* __restrict__ Wtb,
    unsigned short* __restrict__ Qb, unsigned short* __restrict__ Kb,
    unsigned short* __restrict__ Vt)
{
    const int t = threadIdx.x;
    const int w = t >> 6;                // 0:Q 1:K 2:V
    const int l = t & 63;
    const int lo = l & 15, hi = l >> 4;
    const int tok0 = blockIdx.x * 16;
    const int b  = tok0 >> 11;
    const int cb = tok0 & 2047;
    const int tile0 = blockIdx.y * 4;

    // x fragments: lane holds x[tok0+lo][kc*32 + hi*8 .. +8] as bf16
    short8 xb[4];
    const float* xrow = x + (size_t)(tok0 + lo) * IND;
#pragma unroll
    for (int kc = 0; kc < 4; ++kc) {
        const float4 a = *(const float4*)(xrow + kc * 32 + hi * 8);
        const float4 c = *(const float4*)(xrow + kc * 32 + hi * 8 + 4);
        xb[kc] = cvt8(a, c);
    }

    const unsigned short* wbase = Wtb + (size_t)(w * 128) * IND;
#pragma unroll
    for (int tile = 0; tile < 4; ++tile) {
        const int n0 = (tile0 + tile) * 16;
        short8 wf[4];
#pragma unroll
        for (int kc = 0; kc < 4; ++kc)
            wf[kc] = *(const short8*)(wbase + (size_t)(n0 + lo) * IND +
                                      kc * 32 + hi * 8);
        f4t acc = 0.f;
        if (w < 2) {
            // Yt = Wt-rows x x-rows: lane owns token=lo, cols n0+hi*4+r
#pragma unroll
            for (int kc = 0; kc < 4; ++kc) acc = MFMA32(wf[kc], xb[kc], acc);
            us4 v;
#pragma unroll
            for (int r = 0; r < 4; ++r) v[r] = f2bf(acc[r]);
            unsigned short* O = (w == 0) ? Qb : Kb;
            *(us4*)(O + (size_t)(tok0 + lo) * IND + n0 + hi * 4) = v;
        } else {
            // Y = x-rows x W-cols: lane owns d=n0+lo, tokens cb+hi*4+r
#pragma unroll
            for (int kc = 0; kc < 4; ++kc) acc = MFMA32(xb[kc], wf[kc], acc);
            us4 v;
#pragma unroll
            for (int r = 0; r < 4; ++r) v[r] = f2bf(acc[r]);
            *(us4*)(Vt + ((size_t)(b * IND) + n0 + lo) * C_ + cb + hi * 4) = v;
        }
    }
}

// ---------------------------------------------------------------------------
// K2: MFMA flash attention, R14: 32-key chunks + V back to registers.
// R6 post-mortem: busy = VALU 51 + MFMA 10 + LDS 15 = ~75%; the ~25% idle
// is barrier overhead (4 barriers + 2 vmcnts per 32 keys), and LDS bank
// "conflicts" are at the structural wave64-b128 floor (layout is a dead
// lever). So: (1) 32-key chunks halve barriers/vmcnts per key while
// keeping 4 blocks/CU (K 8KB + adj 8KB, dbuf = 32 KB LDS); (2) V is a
// plain register load again (L2-resident). The R0 in-order-vmcnt poison
// is now bounded: the compiler's V(c)-wait can only force retirement of
// stage(c+1), which by then has a full iteration (~1000+ wall cy at 16
// waves/CU) in flight >= HBM latency; V loads stay OLDER than stage(c+2),
// so the counted chunk-top vmcnt(4) stays exact (V already retired by its
// own consumption). Steady loop: vmcnt(4) -> barrier -> compute (V regs,
// K/adj ds_read) -> lgkmcnt(0) -> barrier -> stage(c+2) [4 DMAs].
// XOR swizzles on K and adj via pre-swizzled GLOBAL source (DMA dest
// linear), inverse XOR on ds_read; both verified at the bank floor.
// Math is bit-identical to R0/R6.
__global__ __launch_bounds__(256, 4) void attn_kernel(
    const unsigned short* __restrict__ Qb, const unsigned short* __restrict__ Kb,
    const unsigned short* __restrict__ Vt, const float* __restrict__ adj,
    float* __restrict__ Opart, float* __restrict__ lpart)
{
    __shared__ __align__(16) char Ksm[2][8192];   // [key 0..31][128 d bf16]
    __shared__ __align__(16) char Asm[2][8192];   // [q 0..63][32 keys f32]

    const int t  = threadIdx.x;
    const int s  = t >> 6;               // wave id = q-subtile (0..3)
    const int l  = t & 63;
    const int lo = l & 15, hi = l >> 4;
    const int b  = blockIdx.y;
    const int kz = blockIdx.z;
    const int q0 = blockIdx.x * 64;
    const int qs = q0 + s * 16 + lo;
    const int kzoff = kz * KPG;
    const int NCH = KPG / 32;            // 16 chunks of 32 keys

    // ---- staging sources (per lane, bytes). 4 DMAs/wave/chunk (2 K, 2 adj).
    // K: instr covers 4 key rows x 256B; wave s owns chunk-local keys
    // s*8..s*8+7. Source col pre-swizzled by ((key&7)<<4).
    const int kA = s * 8 + (l >> 4);                 // instr A rows (kA&7 = l>>4)
    const int kB = kA + 4;                           // instr B rows
    const char* srcK_A = (const char*)Kb + ((size_t)(b * C_ + kzoff) + kA) * 256
                         + (((l & 15) * 16) ^ ((kA & 7) << 4));
    const char* srcK_B = (const char*)Kb + ((size_t)(b * C_ + kzoff) + kB) * 256
                         + (((l & 15) * 16) ^ ((kB & 7) << 4));
    // adj: instr covers 8 q rows x 128B; wave s owns q rows s*16..s*16+15.
    // Source col pre-swizzled by ((q&7)<<4); (qA&7)==(qB&7)==l>>3.
    const int qA = s * 16 + (l >> 3);
    const int qB = qA + 8;
    const char* srcA_A = (const char*)adj + ((size_t)(b * C_ + q0 + qA) * C_ + kzoff) * 4
                         + (((l & 7) * 16) ^ ((l >> 3) << 4));
    const char* srcA_B = (const char*)adj + ((size_t)(b * C_ + q0 + qB) * C_ + kzoff) * 4
                         + (((l & 7) * 16) ^ ((l >> 3) << 4));

#if __has_builtin(__builtin_amdgcn_global_load_lds)
#define GLL(gp, lp) __builtin_amdgcn_global_load_lds( \
    (const __attribute__((address_space(1))) unsigned int*)(gp), \
    (__attribute__((address_space(3))) unsigned int*)(lp), 16, 0, 0)
#else
#define GLL(gp, lp) (void)(gp)   // host-pass placeholder
#endif

    auto stage = [&](int c, int buf) {
        GLL(srcK_A + (size_t)c * 8192, Ksm[buf] + (2 * s)     * 1024);
        GLL(srcK_B + (size_t)c * 8192, Ksm[buf] + (2 * s + 1) * 1024);
        GLL(srcA_A + (size_t)c * 128,  Asm[buf] + (2 * s)     * 1024);
        GLL(srcA_B + (size_t)c * 128,  Asm[buf] + (2 * s + 1) * 1024);
    };

    // qf loaded FIRST, then stage(0), stage(1); sched_barrier(0) pins the
    // issue order so the c=0 vmcnt(4) retires exactly qf(4)+stage0(4).
    short8 qf[4];
#pragma unroll
    for (int h = 0; h < 4; ++h)
        qf[h] = *(const short8*)(Qb + ((size_t)(b * C_) + qs) * IND + h * 32 + hi * 8);
    __builtin_amdgcn_sched_barrier(0);
    stage(0, 0);
    __builtin_amdgcn_sched_barrier(0);
    stage(1, 1);
    __builtin_amdgcn_sched_barrier(0);

    f4t acc[4][2];
#pragma unroll
    for (int h = 0; h < 4; ++h) { acc[h][0] = 0.f; acc[h][1] = 0.f; }
    float ls[4] = {0.f, 0.f, 0.f, 0.f};

    const unsigned short* Vrow = Vt + ((size_t)(b * IND) + lo) * C_ + hi * 4;
    const int x7 = (lo & 7) << 4;        // read-side inverse swizzle

    // One 16-key stage: K/adj from LDS buf, V from global (L2).
    auto computeS = [&](int buf, int c, int st) {
        const char* Kl = Ksm[buf];
        const char* Al = Asm[buf];
        const int k0 = kzoff + c * 32 + st * 16;
        short8 kf[4];
#pragma unroll
        for (int h = 0; h < 4; ++h)
            kf[h] = *(const short8*)(Kl + (st * 16 + lo) * 256 +
                                     ((h * 64 + hi * 16) ^ x7));
        const f4t av = *(const f4t*)(Al + (s * 16 + lo) * 128 +
                                     ((st * 64 + hi * 16) ^ x7));
#pragma unroll
        for (int h = 0; h < 4; ++h) {
            const s4t vf0 = *(const s4t*)(Vrow + (size_t)(h * 32) * C_ + k0);
            const s4t vf1 = *(const s4t*)(Vrow + (size_t)(h * 32 + 16) * C_ + k0);
            f4t st4 = MFMA32(kf[h], qf[h], (f4t)0.f);
            float p[4];
#pragma unroll
            for (int r = 0; r < 4; ++r) {
                const float a = st4[r] * av[r];          // adj gate (pre-leaky)
                const float m = fmaxf(a, 0.2f * a);      // LeakyReLU(0.2)
                p[r] = exp2f(m);                         // e^s (L2E pre-folded)
                ls[h] += p[r];
            }
            const s4t pp = pack4_bf16(p[0], p[1], p[2], p[3]);
            acc[h][0] = MFMA16(pp, vf0, acc[h][0]);
            acc[h][1] = MFMA16(pp, vf1, acc[h][1]);
        }
    };

    for (int c = 0; c < NCH; ++c) {
        // counted wait: stage(c)'s 4 DMAs retired (older), stage(c+1)'s 4
        // stay in flight. Last chunk: drain. Raw barrier (NOT __syncthreads:
        // that waits vmcnt(0) and would kill the pipeline).
        if (c + 1 < NCH) { asm volatile("s_waitcnt vmcnt(4)" ::: "memory"); }
        else             { asm volatile("s_waitcnt vmcnt(0)" ::: "memory"); }
        __builtin_amdgcn_sched_barrier(0);
        __builtin_amdgcn_s_barrier();
        __builtin_amdgcn_sched_barrier(0);

        computeS(c & 1, c, 0);
        computeS(c & 1, c, 1);

        // our ds_reads of buf[c&1] retired; fence + barrier before any
        // wave's DMA may overwrite buf[c&1]
        asm volatile("s_waitcnt lgkmcnt(0)" ::: "memory");
        __builtin_amdgcn_sched_barrier(0);
        __builtin_amdgcn_s_barrier();
        __builtin_amdgcn_sched_barrier(0);
        if (c + 2 < NCH) stage(c + 2, c & 1);
    }

    // reduce l over the 4 lane-groups (k quarters) within the wave
#pragma unroll
    for (int h = 0; h < 4; ++h) {
        ls[h] += __shfl_xor(ls[h], 16, 64);
        ls[h] += __shfl_xor(ls[h], 32, 64);
    }

    const size_t BHC   = (size_t)B_ * H_ * C_;
    const size_t obase = (size_t)kz * BHC;

    // each lane writes l for head=hi, q=qs
    const float lw = (hi == 0) ? ls[0] : (hi == 1) ? ls[1] : (hi == 2) ? ls[2] : ls[3];
    lpart[obase + (size_t)(b * H_ + hi) * C_ + qs] = lw;

    // O: PV C-layout: lane owns q = q0+s*16+hi*4+r, d = h*32+dh*16+lo
#pragma unroll
    for (int h = 0; h < 4; ++h) {
        const size_t rb = obase + (size_t)(b * H_ + h) * C_ + q0 + s * 16 + hi * 4;
#pragma unroll
        for (int dh = 0; dh < 2; ++dh)
#pragma unroll
            for (int r = 0; r < 4; ++r)
                Opart[(rb + r) * D_ + dh * 16 + lo] = acc[h][dh][r];
    }
#undef GLL
}

// ---------------------------------------------------------------------------
// K3: combine split-K partials -> AOb (bf16):  AOb = (sum O_kz)/(sum l_kz)
__global__ __launch_bounds__(256) void combine_kernel(
    const float* __restrict__ Opart, const float* __restrict__ lpart,
    unsigned short* __restrict__ AOb)
{
    const int cid = blockIdx.x * 256 + threadIdx.x;   // 0 .. 524287
    const int j   = cid & 7;                          // float4 chunk of D=32
    const int idx = cid >> 3;                         // (b*H+h)*C + q
    const int q  = idx & (C_ - 1);
    const int bh = idx >> 11;
    const int h  = bh & (H_ - 1);
    const int b  = bh >> 2;
    const size_t BHC = (size_t)B_ * H_ * C_;

    float4 acc = {0.f, 0.f, 0.f, 0.f};
    float lsum = 0.f;
#pragma unroll
    for (int kz = 0; kz < KSPLIT; ++kz) {
        const size_t base = (size_t)kz * BHC + idx;
        lsum += lpart[base];
        const float4 v = *(const float4*)(Opart + base * D_ + j * 4);
        acc.x += v.x; acc.y += v.y; acc.z += v.z; acc.w += v.w;
    }
    const float inv = 1.f / lsum;
    us4 o;
    o[0] = f2bf(acc.x * inv); o[1] = f2bf(acc.y * inv);
    o[2] = f2bf(acc.z * inv); o[3] = f2bf(acc.w * inv);
    *(us4*)(AOb + ((size_t)(b * C_) + q) * IND + h * D_ + j * 4) = o;
}

// ---------------------------------------------------------------------------
// K4: output projection via MFMA (transposed-compute -> coalesced float4
// stores with fused bias). Block = 256 = 4 waves = 4 N-quarters; 16 tokens
// per block, grid 1024 -> 4096 waves.
__global__ __launch_bounds__(256) void out_proj_kernel(
    const unsigned short* __restrict__ AOb, const unsigned short* __restrict__ Wtb,
    const float* __restrict__ bo, float* __restrict__ out)
{
    const int t  = threadIdx.x;
    const int w  = t >> 6;               // N-quarter
    const int l  = t & 63;
    const int lo = l & 15, hi = l >> 4;
    const int tok0 = blockIdx.x * 16;

    short8 af[4];
    const unsigned short* arow = AOb + (size_t)(tok0 + lo) * IND;
#pragma unroll
    for (int kc = 0; kc < 4; ++kc)
        af[kc] = *(const short8*)(arow + kc * 32 + hi * 8);

    const unsigned short* wbase = Wtb + (size_t)384 * IND;
#pragma unroll
    for (int tt = 0; tt < 2; ++tt) {
        const int n0 = w * 32 + tt * 16;
        short8 wf[4];
#pragma unroll
        for (int kc = 0; kc < 4; ++kc)
            wf[kc] = *(const short8*)(wbase + (size_t)(n0 + lo) * IND +
                                      kc * 32 + hi * 8);
        f4t acc = 0.f;
#pragma unroll
        for (int kc = 0; kc < 4; ++kc) acc = MFMA32(wf[kc], af[kc], acc);
        const f4t bv = *(const f4t*)(bo + n0 + hi * 4);
        float4 o;
        o.x = acc[0] + bv[0]; o.y = acc[1] + bv[1];
        o.z = acc[2] + bv[2]; o.w = acc[3] + bv[3];
        *(float4*)(out + (size_t)(tok0 + lo) * IND + n0 + hi * 4) = o;
    }
}

// ---------------------------------------------------------------------------
extern "C" void kernel_launch(void* const* d_in, const int* in_sizes, int n_in,
                              void* d_out, int out_size, void* d_ws, size_t ws_size,
                              hipStream_t stream) {
    const float* x   = (const float*)d_in[0];
    const float* adj = (const float*)d_in[1];
    const float* Wq  = (const float*)d_in[2];
    const float* Wk  = (const float*)d_in[3];
    const float* Wv  = (const float*)d_in[4];
    const float* Wo  = (const float*)d_in[5];
    const float* bo  = (const float*)d_in[6];
    float* out = (float*)d_out;

    // workspace (bf16 unless noted): Wtb 128KB; Qb/Kb/Vt 4.2MB each;
    // AOb 4.2MB; Opart fp32 33.6MB; lpart fp32 1MB  -> ~47.5 MB total
    unsigned short* Wtb = (unsigned short*)d_ws;
    unsigned short* Qb  = Wtb + (size_t)512 * IND;
    unsigned short* Kb  = Qb + (size_t)M_ * IND;
    unsigned short* Vt  = Kb + (size_t)M_ * IND;
    unsigned short* AOb = Vt + (size_t)M_ * IND;
    float* Opart = (float*)(AOb + (size_t)M_ * IND);
    float* lpart = Opart + (size_t)KSPLIT * B_ * H_ * C_ * D_;

    hipLaunchKernelGGL(prep_w_kernel, dim3(32), dim3(256), 0, stream,
                       Wq, Wk, Wv, Wo, Wtb);
    hipLaunchKernelGGL(qkv_proj_kernel, dim3(M_ / 16, 2), dim3(192), 0, stream,
                       x, Wtb, Qb, Kb, Vt);
    hipLaunchKernelGGL(attn_kernel, dim3(C_ / 64, B_, KSPLIT), dim3(256), 0, stream,
                       Qb, Kb, Vt, adj, Opart, lpart);
    hipLaunchKernelGGL(combine_kernel, dim3(B_ * H_ * C_ * 8 / 256), dim3(256), 0, stream,
                       Opart, lpart, AOb);
    hipLaunchKernelGGL(out_proj_kernel, dim3(M_ / 16), dim3(256), 0, stream,
                       AOb, Wtb, bo, out);
}

// Round 8
// 285.497 us; speedup vs baseline: 1.1788x; 1.1788x over previous
//
#include <hip/hip_runtime.h>
#include <hip/hip_bf16.h>

// Problem constants (GATLayer): B=8, C=2048, IN=OUT=128, H=4, D=32
constexpr int B_  = 8;
constexpr int C_  = 2048;
constexpr int IND = 128;
constexpr int H_  = 4;
constexpr int D_  = 32;
constexpr int M_  = B_ * C_;          // 16384 tokens
constexpr float QSCALE = 0.17677669529663687f;   // 1/sqrt(32)
constexpr float L2E    = 1.4426950408889634f;
constexpr float QL2    = QSCALE * L2E;           // folded into Wt Q-rows

constexpr int KSPLIT = 4;             // global split (Opart = 33.6 MB, ws fits)
constexpr int KPG = C_ / KSPLIT;      // 512 keys per (block, kz)

typedef __attribute__((ext_vector_type(8))) short short8;
typedef __attribute__((ext_vector_type(4))) short s4t;
typedef __attribute__((ext_vector_type(4))) float f4t;
typedef __attribute__((ext_vector_type(4))) unsigned short us4;

// Device pass has these; host pass doesn't advertise via __has_builtin.
#if __has_builtin(__builtin_amdgcn_mfma_f32_16x16x16bf16_1k)
#define MFMA16(a, b, c) __builtin_amdgcn_mfma_f32_16x16x16bf16_1k(a, b, c, 0, 0, 0)
#else
#define MFMA16(a, b, c) (c)   // host-pass placeholder
#endif
#define MFMA32(a, b, c) __builtin_amdgcn_mfma_f32_16x16x32_bf16(a, b, c, 0, 0, 0)

__device__ __forceinline__ unsigned short f2bf(float f) {
    union { float f; unsigned u; } v; v.f = f;
    unsigned u = v.u + 0x7fffu + ((v.u >> 16) & 1u);   // RNE
    return (unsigned short)(u >> 16);
}

__device__ __forceinline__ s4t pack4_bf16(float p0, float p1, float p2, float p3) {
#if __has_builtin(__builtin_amdgcn_cvt_pk_bf16_f32)
    auto a = __builtin_amdgcn_cvt_pk_bf16_f32(p0, p1);
    auto b = __builtin_amdgcn_cvt_pk_bf16_f32(p2, p3);
    unsigned u[2];
    __builtin_memcpy(&u[0], &a, 4);
    __builtin_memcpy(&u[1], &b, 4);
    s4t pp;
    __builtin_memcpy(&pp, u, 8);
    return pp;
#else
    s4t pp;
    pp[0] = (short)f2bf(p0); pp[1] = (short)f2bf(p1);
    pp[2] = (short)f2bf(p2); pp[3] = (short)f2bf(p3);
    return pp;
#endif
}

__device__ __forceinline__ short8 cvt8(float4 a, float4 b) {
    s4t x = pack4_bf16(a.x, a.y, a.z, a.w);
    s4t y = pack4_bf16(b.x, b.y, b.z, b.w);
    short8 r;
    r[0] = x[0]; r[1] = x[1]; r[2] = x[2]; r[3] = x[3];
    r[4] = y[0]; r[5] = y[1]; r[6] = y[2]; r[7] = y[3];
    return r;
}

// ---------------------------------------------------------------------------
// K0: weight prep. Wtb[512][128] bf16: row n = column n of the fused weight
// [Wq*QL2 | Wk | Wv | Wo].  LDS tile transpose, padded stride.
__global__ __launch_bounds__(256) void prep_w_kernel(
    const float* __restrict__ Wq, const float* __restrict__ Wk,
    const float* __restrict__ Wv, const float* __restrict__ Wo,
    unsigned short* __restrict__ Wtb)
{
    __shared__ unsigned short lds[16][130];
    const int t  = threadIdx.x;
    const int n0 = blockIdx.x * 16;          // 0..511 in steps of 16

    const float* src; int nb; float sc = 1.0f;
    if      (n0 < 128) { src = Wq; nb = n0;       sc = QL2; }
    else if (n0 < 256) { src = Wk; nb = n0 - 128; }
    else if (n0 < 384) { src = Wv; nb = n0 - 256; }
    else               { src = Wo; nb = n0 - 384; }

    const int nn = t & 15, kk = t >> 4;      // kk: 0..15
#pragma unroll
    for (int kb = 0; kb < 8; ++kb) {
        const int k = kb * 16 + kk;
        lds[nn][k] = f2bf(src[k * IND + nb + nn] * sc);
    }
    __syncthreads();
    const int k = t & 127, rr = t >> 7;      // rr: 0..1
#pragma unroll
    for (int it = 0; it < 8; ++it) {
        const int r = it * 2 + rr;
        Wtb[(size_t)(n0 + r) * IND + k] = lds[r][k];
    }
}

// ---------------------------------------------------------------------------
// K1: QKV projection via MFMA. Block = 192 = 3 waves (one per matrix);
// grid (M/16, 2): grid.y splits the 8 N-tiles into two halves -> 6144 waves.
// Q/K computed TRANSPOSED (coalesced 8B row stores); V computed normal ->
// lands directly in Vt[b][d][c] layout.
__global__ __launch_bounds__(192) void qkv_proj_kernel(
    const float* __restrict__ x, const unsigned short* __restrict__ Wtb,
    unsigned short* __restrict__ Qb, unsigned short* __restrict__ Kb,
    unsigned short* __restrict__ Vt)
{
    const int t = threadIdx.x;
    const int w = t >> 6;                // 0:Q 1:K 2:V
    const int l = t & 63;
    const int lo = l & 15, hi = l >> 4;
    const int tok0 = blockIdx.x * 16;
    const int b  = tok0 >> 11;
    const int cb = tok0 & 2047;
    const int tile0 = blockIdx.y * 4;

    // x fragments: lane holds x[tok0+lo][kc*32 + hi*8 .. +8] as bf16
    short8 xb[4];
    const float* xrow = x + (size_t)(tok0 + lo) * IND;
#pragma unroll
    for (int kc = 0; kc < 4; ++kc) {
        const float4 a = *(const float4*)(xrow + kc * 32 + hi * 8);
        const float4 c = *(const float4*)(xrow + kc * 32 + hi * 8 + 4);
        xb[kc] = cvt8(a, c);
    }

    const unsigned short* wbase = Wtb + (size_t)(w * 128) * IND;
#pragma unroll
    for (int tile = 0; tile < 4; ++tile) {
        const int n0 = (tile0 + tile) * 16;
        short8 wf[4];
#pragma unroll
        for (int kc = 0; kc < 4; ++kc)
            wf[kc] = *(const short8*)(wbase + (size_t)(n0 + lo) * IND +
                                      kc * 32 + hi * 8);
        f4t acc = 0.f;
        if (w < 2) {
            // Yt = Wt-rows x x-rows: lane owns token=lo, cols n0+hi*4+r
#pragma unroll
            for (int kc = 0; kc < 4; ++kc) acc = MFMA32(wf[kc], xb[kc], acc);
            us4 v;
#pragma unroll
            for (int r = 0; r < 4; ++r) v[r] = f2bf(acc[r]);
            unsigned short* O = (w == 0) ? Qb : Kb;
            *(us4*)(O + (size_t)(tok0 + lo) * IND + n0 + hi * 4) = v;
        } else {
            // Y = x-rows x W-cols: lane owns d=n0+lo, tokens cb+hi*4+r
#pragma unroll
            for (int kc = 0; kc < 4; ++kc) acc = MFMA32(xb[kc], wf[kc], acc);
            us4 v;
#pragma unroll
            for (int r = 0; r < 4; ++r) v[r] = f2bf(acc[r]);
            *(us4*)(Vt + ((size_t)(b * IND) + n0 + lo) * C_ + cb + hi * 4) = v;
        }
    }
}

// ---------------------------------------------------------------------------
// K2: MFMA flash attention. R16 = R6 (proven 101 us: K/V/adj all staged by
// global_load_lds, consumed by ds_read, counted vmcnt only) with the
// double buffer widened to a TRIPLE buffer (3 x 12 KB = 36 KB, still 4
// blocks/CU) so the second per-chunk barrier + lgkmcnt fence can go:
// stage(c+2) overwrites buf[(c-1)%3], and every wave's reads of that
// buffer were consumed (compiler lgkmcnt waits feed the MFMAs) before it
// could reach the iter-c top barrier. Loop = vmcnt(3) -> ONE barrier ->
// stage(c+2) issued EARLY (DMA hides under compute) -> compute(c).
// R7 lesson (kept): nothing consumed in the steady loop may share the
// vmcnt queue with the DMA pipeline -- V stays in LDS.
// Math is bit-identical to R0/R5/R6.
__global__ __launch_bounds__(256, 4) void attn_kernel(
    const unsigned short* __restrict__ Qb, const unsigned short* __restrict__ Kb,
    const unsigned short* __restrict__ Vt, const float* __restrict__ adj,
    float* __restrict__ Opart, float* __restrict__ lpart)
{
    __shared__ __align__(16) char Ksm[3][4096];   // [key 0..15][128 d bf16]
    __shared__ __align__(16) char Vsm[3][4096];   // [d 0..127][16 keys bf16]
    __shared__ __align__(16) char Asm[3][4096];   // [q 0..63][16 keys f32]

    const int t  = threadIdx.x;
    const int s  = t >> 6;               // wave id = q-subtile (0..3)
    const int l  = t & 63;
    const int lo = l & 15, hi = l >> 4;
    const int b  = blockIdx.y;
    const int kz = blockIdx.z;
    const int q0 = blockIdx.x * 64;
    const int qs = q0 + s * 16 + lo;
    const int kzoff = kz * KPG;
    const int NCH = KPG / 16;            // 32 chunks of 16 keys

    // ---- staging source addresses (per lane, bytes). Each wave stages
    // 1 KB per stream per chunk (3 DMAs), LDS dest = wave base + l*16. ----
    // K: wave s covers chunk-local key rows s*4 .. s*4+3 (4 x 256B).
    //    Source col pre-swizzled by ((key&7)<<4); LDS stays linear.
    const int keyS = s * 4 + (l >> 4);               // chunk-local key row
    const char* srcK = (const char*)Kb + ((size_t)(b * C_ + kzoff) + keyS) * 256
                       + (((l & 15) * 16) ^ ((keyS & 7) << 4));
    // V: wave s covers d rows s*32 .. s*32+31 (32 x 32B); lane = half-row.
    const int dS = s * 32 + (l >> 1);
    const char* srcV = (const char*)Vt + (size_t)(b * IND + dS) * (C_ * 2)
                       + (size_t)kzoff * 2 + (l & 1) * 16;
    // adj: wave s covers q rows s*16 .. s*16+15 (16 x 64B); lane = quarter.
    const int qS = s * 16 + (l >> 2);
    const char* srcA = (const char*)adj
                       + ((size_t)(b * C_ + q0 + qS) * C_ + kzoff) * 4
                       + (l & 3) * 16;

#if __has_builtin(__builtin_amdgcn_global_load_lds)
#define GLL(gp, lp) __builtin_amdgcn_global_load_lds( \
    (const __attribute__((address_space(1))) unsigned int*)(gp), \
    (__attribute__((address_space(3))) unsigned int*)(lp), 16, 0, 0)
#else
#define GLL(gp, lp) (void)(gp)   // host-pass placeholder
#endif

    auto stage = [&](int c, int buf) {
        GLL(srcK + (size_t)c * 4096, Ksm[buf] + s * 1024);   // keys advance 16*256B
        GLL(srcV + (size_t)c * 32,   Vsm[buf] + s * 1024);   // keys advance 16*2B
        GLL(srcA + (size_t)c * 64,   Asm[buf] + s * 1024);   // keys advance 16*4B
    };

    // qf loaded FIRST, then stage(0), stage(1); sched_barrier(0) pins the
    // issue order so the c=0 vmcnt(3) retires exactly qf(4)+stage0(3),
    // keeping stage1's 3 in flight.
    short8 qf[4];
#pragma unroll
    for (int h = 0; h < 4; ++h)
        qf[h] = *(const short8*)(Qb + ((size_t)(b * C_) + qs) * IND + h * 32 + hi * 8);
    __builtin_amdgcn_sched_barrier(0);
    stage(0, 0);
    __builtin_amdgcn_sched_barrier(0);
    stage(1, 1);
    __builtin_amdgcn_sched_barrier(0);

    f4t acc[4][2];
#pragma unroll
    for (int h = 0; h < 4; ++h) { acc[h][0] = 0.f; acc[h][1] = 0.f; }
    float ls[4] = {0.f, 0.f, 0.f, 0.f};

    const int x7 = (lo & 7) << 4;        // K read swizzle (inverse of source)

    auto computeC = [&](int buf) {
        const char* Kl = Ksm[buf];
        const char* Vl = Vsm[buf];
        const char* Al = Asm[buf];
        short8 kf[4];
#pragma unroll
        for (int h = 0; h < 4; ++h)
            kf[h] = *(const short8*)(Kl + lo * 256 + ((h * 64 + hi * 16) ^ x7));
        s4t vf[8];
#pragma unroll
        for (int h = 0; h < 4; ++h) {
            vf[h * 2]     = *(const s4t*)(Vl + (h * 32 + lo) * 32 + hi * 8);
            vf[h * 2 + 1] = *(const s4t*)(Vl + (h * 32 + 16 + lo) * 32 + hi * 8);
        }
        const f4t av = *(const f4t*)(Al + (s * 16 + lo) * 64 + hi * 16);
#pragma unroll
        for (int h = 0; h < 4; ++h) {
            f4t st4 = MFMA32(kf[h], qf[h], (f4t)0.f);
            float p[4];
#pragma unroll
            for (int r = 0; r < 4; ++r) {
                const float a = st4[r] * av[r];          // adj gate (pre-leaky)
                const float m = fmaxf(a, 0.2f * a);      // LeakyReLU(0.2)
                p[r] = exp2f(m);                         // e^s (L2E pre-folded)
                ls[h] += p[r];
            }
            const s4t pp = pack4_bf16(p[0], p[1], p[2], p[3]);
            acc[h][0] = MFMA16(pp, vf[h * 2], acc[h][0]);
            acc[h][1] = MFMA16(pp, vf[h * 2 + 1], acc[h][1]);
        }
    };

    int bc = 0, bn = 1, bs = 2;          // current / next / spare buffers
    for (int c = 0; c < NCH; ++c) {
        // counted wait: stage(c)'s 3 DMAs retired (older), stage(c+1)'s 3
        // stay in flight. Last chunk: drain. ONE raw barrier (NOT
        // __syncthreads: that waits vmcnt(0) and would kill the pipeline).
        if (c + 1 < NCH) { asm volatile("s_waitcnt vmcnt(3)" ::: "memory"); }
        else             { asm volatile("s_waitcnt vmcnt(0)" ::: "memory"); }
        __builtin_amdgcn_sched_barrier(0);
        __builtin_amdgcn_s_barrier();
        __builtin_amdgcn_sched_barrier(0);

        // stage early: buf bs = buf[(c-1)%3]; all waves' reads of it were
        // consumed before they could pass the barrier above.
        if (c + 2 < NCH) stage(c + 2, bs);
        computeC(bc);

        const int tmp = bc; bc = bn; bn = bs; bs = tmp;
    }

    // reduce l over the 4 lane-groups (k quarters) within the wave
#pragma unroll
    for (int h = 0; h < 4; ++h) {
        ls[h] += __shfl_xor(ls[h], 16, 64);
        ls[h] += __shfl_xor(ls[h], 32, 64);
    }

    const size_t BHC   = (size_t)B_ * H_ * C_;
    const size_t obase = (size_t)kz * BHC;

    // each lane writes l for head=hi, q=qs
    const float lw = (hi == 0) ? ls[0] : (hi == 1) ? ls[1] : (hi == 2) ? ls[2] : ls[3];
    lpart[obase + (size_t)(b * H_ + hi) * C_ + qs] = lw;

    // O: PV C-layout: lane owns q = q0+s*16+hi*4+r, d = h*32+dh*16+lo
#pragma unroll
    for (int h = 0; h < 4; ++h) {
        const size_t rb = obase + (size_t)(b * H_ + h) * C_ + q0 + s * 16 + hi * 4;
#pragma unroll
        for (int dh = 0; dh < 2; ++dh)
#pragma unroll
            for (int r = 0; r < 4; ++r)
                Opart[(rb + r) * D_ + dh * 16 + lo] = acc[h][dh][r];
    }
#undef GLL
}

// ---------------------------------------------------------------------------
// K3 (fused combine + output projection). R16: removes the separate
// combine kernel (one less dispatch + sync; 43 -> 35 MB traffic).
// Phase 1: wave w computes head w's combine for the block's 16 tokens
// with fully-coalesced Opart reads (per (kz,head) region is 16 rows x
// 32 f32 = 2 KB contiguous; lane j takes float4 j and j+64), divides by
// the lpart sum, packs bf16 (same RNE as before), parks in a 4 KB
// swizzled LDS tile. Phase 2: the original MFMA GEMM reads its A
// fragments from that tile. Bit-identical rounding to the old AOb path.
__global__ __launch_bounds__(256) void out_proj_kernel(
    const float* __restrict__ Opart, const float* __restrict__ lpart,
    const unsigned short* __restrict__ Wtb, const float* __restrict__ bo,
    float* __restrict__ out)
{
    __shared__ __align__(16) char AOsm[4096];    // [16 tok][128 col bf16], swz

    const int t  = threadIdx.x;
    const int w  = t >> 6;               // wave = head (phase 1) / N-quarter (phase 2)
    const int l  = t & 63;
    const int lo = l & 15, hi = l >> 4;
    const int tok0 = blockIdx.x * 16;
    const int b  = tok0 >> 11;           // 16-token blocks never cross b
    const int q0 = tok0 & 2047;
    const size_t BHC = (size_t)B_ * H_ * C_;

    // ---- phase 1: combine head w for tokens tok0..tok0+15 ----
    {
        const int ra = l >> 3;           // token row a (0..7), b row = ra+8
        const int dq = l & 7;            // float4 index within 32-f row
        float4 va = {0.f, 0.f, 0.f, 0.f}, vb = {0.f, 0.f, 0.f, 0.f};
        float la = 0.f, lb = 0.f;
#pragma unroll
        for (int kz = 0; kz < KSPLIT; ++kz) {
            const size_t rowb = (size_t)kz * BHC + (size_t)(b * H_ + w) * C_ + q0;
            la += lpart[rowb + ra];
            lb += lpart[rowb + ra + 8];
            const float* R = Opart + rowb * D_;
            const float4 u = *(const float4*)(R + l * 4);          // row ra
            const float4 v = *(const float4*)(R + 256 + l * 4);    // row ra+8
            va.x += u.x; va.y += u.y; va.z += u.z; va.w += u.w;
            vb.x += v.x; vb.y += v.y; vb.z += v.z; vb.w += v.w;
        }
        const float ia = 1.f / la, ib = 1.f / lb;
        const s4t pa = pack4_bf16(va.x * ia, va.y * ia, va.z * ia, va.w * ia);
        const s4t pb = pack4_bf16(vb.x * ib, vb.y * ib, vb.z * ib, vb.w * ib);
        const int colb = w * 64 + dq * 8;            // byte col of d-quad
        *(s4t*)(AOsm + ra * 256       + (colb ^ ((ra & 7) << 4))) = pa;
        *(s4t*)(AOsm + (ra + 8) * 256 + (colb ^ ((ra & 7) << 4))) = pb;
    }
    __syncthreads();

    // ---- phase 2: GEMM vs Wo (unchanged math) ----
    short8 af[4];
#pragma unroll
    for (int kc = 0; kc < 4; ++kc)
        af[kc] = *(const short8*)(AOsm + lo * 256 +
                                  ((kc * 64 + hi * 16) ^ ((lo & 7) << 4)));

    const unsigned short* wbase = Wtb + (size_t)384 * IND;
#pragma unroll
    for (int tt = 0; tt < 2; ++tt) {
        const int n0 = w * 32 + tt * 16;
        short8 wf[4];
#pragma unroll
        for (int kc = 0; kc < 4; ++kc)
            wf[kc] = *(const short8*)(wbase + (size_t)(n0 + lo) * IND +
                                      kc * 32 + hi * 8);
        f4t acc = 0.f;
#pragma unroll
        for (int kc = 0; kc < 4; ++kc) acc = MFMA32(wf[kc], af[kc], acc);
        const f4t bv = *(const f4t*)(bo + n0 + hi * 4);
        float4 o;
        o.x = acc[0] + bv[0]; o.y = acc[1] + bv[1];
        o.z = acc[2] + bv[2]; o.w = acc[3] + bv[3];
        *(float4*)(out + (size_t)(tok0 + lo) * IND + n0 + hi * 4) = o;
    }
}

// ---------------------------------------------------------------------------
extern "C" void kernel_launch(void* const* d_in, const int* in_sizes, int n_in,
                              void* d_out, int out_size, void* d_ws, size_t ws_size,
                              hipStream_t stream) {
    const float* x   = (const float*)d_in[0];
    const float* adj = (const float*)d_in[1];
    const float* Wq  = (const float*)d_in[2];
    const float* Wk  = (const float*)d_in[3];
    const float* Wv  = (const float*)d_in[4];
    const float* Wo  = (const float*)d_in[5];
    const float* bo  = (const float*)d_in[6];
    float* out = (float*)d_out;

    // workspace (bf16 unless noted): Wtb 128KB; Qb/Kb/Vt 4.2MB each;
    // (AOb slot retained, unused since R16); Opart fp32 33.6MB; lpart 1MB
    unsigned short* Wtb = (unsigned short*)d_ws;
    unsigned short* Qb  = Wtb + (size_t)512 * IND;
    unsigned short* Kb  = Qb + (size_t)M_ * IND;
    unsigned short* Vt  = Kb + (size_t)M_ * IND;
    unsigned short* AOb = Vt + (size_t)M_ * IND;   // unused (layout keeper)
    float* Opart = (float*)(AOb + (size_t)M_ * IND);
    float* lpart = Opart + (size_t)KSPLIT * B_ * H_ * C_ * D_;

    hipLaunchKernelGGL(prep_w_kernel, dim3(32), dim3(256), 0, stream,
                       Wq, Wk, Wv, Wo, Wtb);
    hipLaunchKernelGGL(qkv_proj_kernel, dim3(M_ / 16, 2), dim3(192), 0, stream,
                       x, Wtb, Qb, Kb, Vt);
    hipLaunchKernelGGL(attn_kernel, dim3(C_ / 64, B_, KSPLIT), dim3(256), 0, stream,
                       Qb, Kb, Vt, adj, Opart, lpart);
    hipLaunchKernelGGL(out_proj_kernel, dim3(M_ / 16), dim3(256), 0, stream,
                       Opart, lpart, Wtb, bo, out);
}